// Round 4
// baseline (178.591 us; speedup 1.0000x reference)
//
#include <hip/hip_runtime.h>

// x: (N=4, C=256, H=128, W=128) f32 NCHW; rois: (K,5) f32; out: (K,256,7,7) f32
#define NB    4
#define CCH   256
#define HH    128
#define WW    128
#define HW    (HH * WW)           // 16384
#define CHW   (CCH * HW)          // 4194304 = 1<<22
#define PBINS 49                  // 7*7
#define OUT_PER_ROI (CCH * PBINS) // 12544

typedef __attribute__((ext_vector_type(8))) unsigned short ushort8_t;

__device__ __forceinline__ unsigned short f2bf(float f) {
  unsigned u = __float_as_uint(f);
  unsigned r = u + 0x7fffu + ((u >> 16) & 1u);   // round-to-nearest-even
  return (unsigned short)(r >> 16);
}

__device__ __forceinline__ float4 ld4bf(const unsigned short* p) {
  ushort4 v = *(const ushort4*)p;                 // 8B load (4 bf16)
  return make_float4(__uint_as_float((unsigned)v.x << 16),
                     __uint_as_float((unsigned)v.y << 16),
                     __uint_as_float((unsigned)v.z << 16),
                     __uint_as_float((unsigned)v.w << 16));
}

// ---------------------------------------------------------------------------
// Kernel 1: NCHW f32 -> NHWC bf16 transpose, 64ch x 64hw tiles.
// Loads float4; stores ushort8 (16B). LDS [64][65] f32: both phases <=2-way
// bank aliasing (free).
// ---------------------------------------------------------------------------
__global__ __launch_bounds__(256) void xpose_nchw_nhwc_bf16(
    const float* __restrict__ src, unsigned short* __restrict__ dst) {
  __shared__ float tile[64][65];
  const int n   = blockIdx.z;
  const int hw0 = blockIdx.x * 64;
  const int c0  = blockIdx.y * 64;
  const float* s = src + (size_t)n * CHW;
  unsigned short* d = dst + (size_t)n * CHW;
  const int tid = threadIdx.x;
  const int tx = tid & 15, ty = tid >> 4;        // 16 x 16

#pragma unroll
  for (int r = 0; r < 4; ++r) {
    const int c = ty + 16 * r;                   // 0..63
    const float4 v = *(const float4*)(s + (size_t)(c0 + c) * HW + hw0 + 4 * tx);
    tile[c][4 * tx + 0] = v.x;
    tile[c][4 * tx + 1] = v.y;
    tile[c][4 * tx + 2] = v.z;
    tile[c][4 * tx + 3] = v.w;
  }
  __syncthreads();

  const int row = tid >> 3;                      // 0..31 (hw within tile)
  const int cg  = tid & 7;                       // channel group of 8
#pragma unroll
  for (int r = 0; r < 2; ++r) {
    const int h = row + 32 * r;                  // 0..63
    ushort8_t o;
#pragma unroll
    for (int j = 0; j < 8; ++j) o[j] = f2bf(tile[cg * 8 + j][h]);
    *(ushort8_t*)(d + (size_t)(hw0 + h) * CCH + c0 + cg * 8) = o;
  }
}

// ---------------------------------------------------------------------------
// Kernel 2: ROI align over bf16 NHWC map. One block (512 thr = 8 waves) per
// ROI. Branchless: valid-mask folded into precomputed sample weights; corner
// element offsets precomputed. Wave w handles bin pair (p, p+8) for MLP.
// Results staged in LDS in output layout -> one contiguous float4 copy.
// ---------------------------------------------------------------------------
__device__ __forceinline__ float4 bin_compute(
    const unsigned short* __restrict__ xbase, int p,
    const float* __restrict__ wy0, const float* __restrict__ wy1,
    const float* __restrict__ wx0, const float* __restrict__ wx1,
    const int (*__restrict__ oy)[2], const int (*__restrict__ ox)[2]) {
  const int ph = p / 7, pw = p - 7 * ph;
  float4 a = make_float4(0.f, 0.f, 0.f, 0.f);
#pragma unroll
  for (int iy = 0; iy < 2; ++iy) {
    const int   gy  = 2 * ph + iy;
    const float wyA = wy0[gy], wyB = wy1[gy];
    const int   oyA = oy[gy][0], oyB = oy[gy][1];
#pragma unroll
    for (int ix = 0; ix < 2; ++ix) {
      const int   gx  = 2 * pw + ix;
      const float wxA = wx0[gx], wxB = wx1[gx];
      const int   oxA = ox[gx][0], oxB = ox[gx][1];
      const float4 c00 = ld4bf(xbase + oyA + oxA);
      const float4 c01 = ld4bf(xbase + oyA + oxB);
      const float4 c10 = ld4bf(xbase + oyB + oxA);
      const float4 c11 = ld4bf(xbase + oyB + oxB);
      const float w00 = wyA * wxA, w01 = wyA * wxB;
      const float w10 = wyB * wxA, w11 = wyB * wxB;
      a.x += w00 * c00.x + w01 * c01.x + w10 * c10.x + w11 * c11.x;
      a.y += w00 * c00.y + w01 * c01.y + w10 * c10.y + w11 * c11.y;
      a.z += w00 * c00.z + w01 * c01.z + w10 * c10.z + w11 * c11.z;
      a.w += w00 * c00.w + w01 * c01.w + w10 * c10.w + w11 * c11.w;
    }
  }
  return a;
}

__global__ __launch_bounds__(512, 6) void roi_align_nhwc_bf16(
    const unsigned short* __restrict__ xt, const float* __restrict__ rois,
    float* __restrict__ out) {
  __shared__ float s_pool[OUT_PER_ROI];   // 49 KB
  __shared__ float s_wy0[14], s_wy1[14], s_wx0[14], s_wx1[14];
  __shared__ int   s_oy[14][2], s_ox[14][2];

  const int k   = blockIdx.x;
  const int tid = threadIdx.x;
  const float* r = rois + 5 * k;
  const int   n  = (int)r[0];
  const float sx = r[1] * 0.0625f, sy = r[2] * 0.0625f;
  const float ex = r[3] * 0.0625f, ey = r[4] * 0.0625f;
  const float rw = fmaxf(ex - sx, 1.0f);
  const float rh = fmaxf(ey - sy, 1.0f);

  if (tid < 14) {                       // y metadata
    float g  = ((float)tid + 0.5f) * 0.5f;
    float v  = sy + (rh / 7.0f) * g;
    float m  = ((v > -1.0f) && (v < 128.0f)) ? 1.0f : 0.0f;
    float vc = fminf(fmaxf(v, 0.0f), 127.0f);
    int   lo = (int)floorf(vc);
    float fy = vc - (float)lo;
    s_wy0[tid] = (1.0f - fy) * m;
    s_wy1[tid] = fy * m;
    s_oy[tid][0] = lo << 15;
    s_oy[tid][1] = min(lo + 1, 127) << 15;
  } else if (tid >= 64 && tid < 78) {   // x metadata
    int   j  = tid - 64;
    float g  = ((float)j + 0.5f) * 0.5f;
    float v  = sx + (rw / 7.0f) * g;
    float m  = ((v > -1.0f) && (v < 128.0f)) ? 1.0f : 0.0f;
    float vc = fminf(fmaxf(v, 0.0f), 127.0f);
    int   lo = (int)floorf(vc);
    float fx = vc - (float)lo;
    s_wx0[j] = (1.0f - fx) * m;
    s_wx1[j] = fx * m;
    s_ox[j][0] = lo << 8;
    s_ox[j][1] = min(lo + 1, 127) << 8;
  }
  __syncthreads();

  const int wv   = tid >> 6;            // 0..7
  const int lane = tid & 63;
  const unsigned short* xbase = xt + ((size_t)n << 22) + (lane << 2);
  const int cb = lane << 2;

  for (int p0 = wv; p0 < PBINS; p0 += 16) {
    const int p1 = p0 + 8;
    float4 a0 = bin_compute(xbase, p0, s_wy0, s_wy1, s_wx0, s_wx1, s_oy, s_ox);
    float4 a1 = make_float4(0.f, 0.f, 0.f, 0.f);
    if (p1 < PBINS)
      a1 = bin_compute(xbase, p1, s_wy0, s_wy1, s_wx0, s_wx1, s_oy, s_ox);
    s_pool[(cb + 0) * PBINS + p0] = a0.x * 0.25f;
    s_pool[(cb + 1) * PBINS + p0] = a0.y * 0.25f;
    s_pool[(cb + 2) * PBINS + p0] = a0.z * 0.25f;
    s_pool[(cb + 3) * PBINS + p0] = a0.w * 0.25f;
    if (p1 < PBINS) {
      s_pool[(cb + 0) * PBINS + p1] = a1.x * 0.25f;
      s_pool[(cb + 1) * PBINS + p1] = a1.y * 0.25f;
      s_pool[(cb + 2) * PBINS + p1] = a1.z * 0.25f;
      s_pool[(cb + 3) * PBINS + p1] = a1.w * 0.25f;
    }
  }
  __syncthreads();

  float4*       op = (float4*)(out + (size_t)k * OUT_PER_ROI);
  const float4* sp = (const float4*)s_pool;
  for (int i = tid; i < OUT_PER_ROI / 4; i += 512) op[i] = sp[i];
}

// ---------------------------------------------------------------------------
// Fallback: direct NCHW gather (only if workspace too small).
// ---------------------------------------------------------------------------
__global__ __launch_bounds__(256) void roi_align_nchw(
    const float* __restrict__ x, const float* __restrict__ rois,
    float* __restrict__ out, int total) {
  int idx = blockIdx.x * 256 + threadIdx.x;
  if (idx >= total) return;
  int k  = idx / OUT_PER_ROI;
  int rr = idx - k * OUT_PER_ROI;
  int c  = rr / PBINS;
  int p  = rr - c * PBINS;
  int ph = p / 7, pw = p - 7 * ph;
  const float* r = rois + 5 * k;
  int   n  = (int)r[0];
  float sx = r[1] * 0.0625f, sy = r[2] * 0.0625f;
  float ex = r[3] * 0.0625f, ey = r[4] * 0.0625f;
  float rw = fmaxf(ex - sx, 1.0f);
  float rh = fmaxf(ey - sy, 1.0f);
  const float* xb = x + ((size_t)n * CCH + c) * HW;
  float acc = 0.f;
  for (int iy = 0; iy < 2; ++iy) {
    float g  = (float)(2 * ph + iy) + 0.5f;
    float v  = sy + (rh / 7.0f) * (g * 0.5f);
    if (!(v > -1.0f && v < 128.0f)) continue;
    float vc = fminf(fmaxf(v, 0.0f), 127.0f);
    int   y0 = (int)floorf(vc);
    int   y1 = min(y0 + 1, 127);
    float fy = vc - (float)y0;
    for (int ix = 0; ix < 2; ++ix) {
      float gx  = (float)(2 * pw + ix) + 0.5f;
      float vx_ = sx + (rw / 7.0f) * (gx * 0.5f);
      if (!(vx_ > -1.0f && vx_ < 128.0f)) continue;
      float vcx = fminf(fmaxf(vx_, 0.0f), 127.0f);
      int   x0  = (int)floorf(vcx);
      int   x1  = min(x0 + 1, 127);
      float fx  = vcx - (float)x0;
      float v00 = xb[y0 * WW + x0], v01 = xb[y0 * WW + x1];
      float v10 = xb[y1 * WW + x0], v11 = xb[y1 * WW + x1];
      acc += v00 * (1.f - fy) * (1.f - fx) + v01 * (1.f - fy) * fx +
             v10 * fy * (1.f - fx) + v11 * fy * fx;
    }
  }
  out[idx] = acc * 0.25f;
}

extern "C" void kernel_launch(void* const* d_in, const int* in_sizes, int n_in,
                              void* d_out, int out_size, void* d_ws, size_t ws_size,
                              hipStream_t stream) {
  const float* x    = (const float*)d_in[0];
  const float* rois = (const float*)d_in[1];
  float*       out  = (float*)d_out;
  const int K = in_sizes[1] / 5;

  const size_t need = (size_t)NB * CHW * sizeof(unsigned short);  // 32 MB
  if (ws_size >= need) {
    unsigned short* xt = (unsigned short*)d_ws;
    dim3 tb(256, 1, 1);
    dim3 tg(HW / 64, CCH / 64, NB);  // 256 x 4 x 4
    xpose_nchw_nhwc_bf16<<<tg, tb, 0, stream>>>(x, xt);
    roi_align_nhwc_bf16<<<K, 512, 0, stream>>>(xt, rois, out);
  } else {
    const int total = K * OUT_PER_ROI;
    roi_align_nchw<<<(total + 255) / 256, 256, 0, stream>>>(x, rois, out, total);
  }
}

// Round 5
// 148.083 us; speedup vs baseline: 1.2060x; 1.2060x over previous
//
#include <hip/hip_runtime.h>

// x: (N=4, C=256, H=128, W=128) f32 NCHW; rois: (K,5) f32; out: (K,256,7,7) f32
#define NB    4
#define CCH   256
#define HH    128
#define WW    128
#define HW    (HH * WW)           // 16384
#define CHW   (CCH * HW)          // 4194304 = 1<<22
#define PBINS 49                  // 7*7
#define OUT_PER_ROI (CCH * PBINS) // 12544

typedef __attribute__((ext_vector_type(8))) unsigned short ushort8_t;

__device__ __forceinline__ unsigned short f2bf(float f) {
  unsigned u = __float_as_uint(f);
  unsigned r = u + 0x7fffu + ((u >> 16) & 1u);   // round-to-nearest-even
  return (unsigned short)(r >> 16);
}
__device__ __forceinline__ float bf2f(unsigned short u) {
  return __uint_as_float((unsigned)u << 16);
}

// ---------------------------------------------------------------------------
// Kernel 1: NCHW -> NHWC f32 transpose, 64x64 tiles, float4 both sides
// (identical to round-2 proven version).
// ---------------------------------------------------------------------------
__global__ __launch_bounds__(256) void xpose_nchw_nhwc(
    const float* __restrict__ src, float* __restrict__ dst) {
  __shared__ float tile[64][65];
  const int n   = blockIdx.z;
  const int hw0 = blockIdx.x * 64;
  const int c0  = blockIdx.y * 64;
  const float* s = src + (size_t)n * CHW;
  float*       d = dst + (size_t)n * CHW;
  const int tx = threadIdx.x;  // 0..15
  const int ty = threadIdx.y;  // 0..15

#pragma unroll
  for (int r = 0; r < 4; ++r) {
    const int c = ty + 16 * r;
    const float4 v = *(const float4*)(s + (size_t)(c0 + c) * HW + hw0 + 4 * tx);
    tile[c][4 * tx + 0] = v.x;
    tile[c][4 * tx + 1] = v.y;
    tile[c][4 * tx + 2] = v.z;
    tile[c][4 * tx + 3] = v.w;
  }
  __syncthreads();
#pragma unroll
  for (int r = 0; r < 4; ++r) {
    const int h = ty + 16 * r;
    float4 v;
    v.x = tile[4 * tx + 0][h];
    v.y = tile[4 * tx + 1][h];
    v.z = tile[4 * tx + 2][h];
    v.w = tile[4 * tx + 3][h];
    *(float4*)(d + (size_t)(hw0 + h) * CCH + c0 + 4 * tx) = v;
  }
}

// ---------------------------------------------------------------------------
// Kernel 2: ROI align over f32 NHWC map — round-2 structure verbatim, with
// ONE change: s_pool staged as bf16 (25 KB instead of 49 KB) so 4 blocks/CU
// fit (32 waves/CU, wave-capped) instead of 3 (24).
// ---------------------------------------------------------------------------
__global__ __launch_bounds__(512) void roi_align_nhwc(
    const float* __restrict__ xt, const float* __restrict__ rois,
    float* __restrict__ out) {
  __shared__ unsigned short s_pool[OUT_PER_ROI];   // 24.5 KB (bf16)
  __shared__ float s_fy[14], s_fx[14];
  __shared__ int   s_y0[14], s_y1[14], s_x0[14], s_x1[14], s_vy[14], s_vx[14];

  const int k   = blockIdx.x;
  const int tid = threadIdx.x;
  const float* r = rois + 5 * k;
  const int   n  = (int)r[0];
  const float sx = r[1] * 0.0625f, sy = r[2] * 0.0625f;
  const float ex = r[3] * 0.0625f, ey = r[4] * 0.0625f;
  const float rw = fmaxf(ex - sx, 1.0f);
  const float rh = fmaxf(ey - sy, 1.0f);

  if (tid < 14) {                       // y metadata
    float g  = ((float)tid + 0.5f) * 0.5f;
    float v  = sy + (rh / 7.0f) * g;
    int   ok = (v > -1.0f) && (v < 128.0f);
    float vc = fminf(fmaxf(v, 0.0f), 127.0f);
    int   lo = (int)floorf(vc);
    s_y0[tid] = lo;
    s_y1[tid] = min(lo + 1, 127);
    s_fy[tid] = vc - (float)lo;
    s_vy[tid] = ok;
  } else if (tid >= 64 && tid < 78) {   // x metadata
    int   j  = tid - 64;
    float g  = ((float)j + 0.5f) * 0.5f;
    float v  = sx + (rw / 7.0f) * g;
    int   ok = (v > -1.0f) && (v < 128.0f);
    float vc = fminf(fmaxf(v, 0.0f), 127.0f);
    int   lo = (int)floorf(vc);
    s_x0[j] = lo;
    s_x1[j] = min(lo + 1, 127);
    s_fx[j] = vc - (float)lo;
    s_vx[j] = ok;
  }
  __syncthreads();

  const int wv   = tid >> 6;            // 0..7
  const int lane = tid & 63;
  const float* xbase = xt + ((size_t)n << 22) + (lane << 2);

  for (int p = wv; p < PBINS; p += 8) {
    const int ph = p / 7;
    const int pw = p - 7 * ph;
    float a0 = 0.f, a1 = 0.f, a2 = 0.f, a3 = 0.f;
#pragma unroll
    for (int iy = 0; iy < 2; ++iy) {
      const int   gy = 2 * ph + iy;
      const int   vy = s_vy[gy];
      const float fy = s_fy[gy];
      const int   y0 = s_y0[gy], y1 = s_y1[gy];
#pragma unroll
      for (int ix = 0; ix < 2; ++ix) {
        const int gx = 2 * pw + ix;
        if (vy && s_vx[gx]) {
          const float fx = s_fx[gx];
          const int   x0 = s_x0[gx], x1 = s_x1[gx];
          const float4 v00 = *(const float4*)(xbase + (y0 << 15) + (x0 << 8));
          const float4 v01 = *(const float4*)(xbase + (y0 << 15) + (x1 << 8));
          const float4 v10 = *(const float4*)(xbase + (y1 << 15) + (x0 << 8));
          const float4 v11 = *(const float4*)(xbase + (y1 << 15) + (x1 << 8));
          const float w00 = (1.f - fy) * (1.f - fx);
          const float w01 = (1.f - fy) * fx;
          const float w10 = fy * (1.f - fx);
          const float w11 = fy * fx;
          a0 += w00 * v00.x + w01 * v01.x + w10 * v10.x + w11 * v11.x;
          a1 += w00 * v00.y + w01 * v01.y + w10 * v10.y + w11 * v11.y;
          a2 += w00 * v00.z + w01 * v01.z + w10 * v10.z + w11 * v11.z;
          a3 += w00 * v00.w + w01 * v01.w + w10 * v10.w + w11 * v11.w;
        }
      }
    }
    const int cb = lane << 2;
    s_pool[(cb + 0) * PBINS + p] = f2bf(a0 * 0.25f);
    s_pool[(cb + 1) * PBINS + p] = f2bf(a1 * 0.25f);
    s_pool[(cb + 2) * PBINS + p] = f2bf(a2 * 0.25f);
    s_pool[(cb + 3) * PBINS + p] = f2bf(a3 * 0.25f);
  }
  __syncthreads();

  // Expand bf16 pool -> f32 output; contiguous 32B per lane per iteration.
  float4*          op = (float4*)(out + (size_t)k * OUT_PER_ROI);
  const ushort8_t* sp = (const ushort8_t*)s_pool;
  for (int i = tid; i < OUT_PER_ROI / 8; i += 512) {   // 1568
    const ushort8_t v = sp[i];
    float4 lo, hi;
    lo.x = bf2f(v[0]); lo.y = bf2f(v[1]); lo.z = bf2f(v[2]); lo.w = bf2f(v[3]);
    hi.x = bf2f(v[4]); hi.y = bf2f(v[5]); hi.z = bf2f(v[6]); hi.w = bf2f(v[7]);
    op[2 * i]     = lo;
    op[2 * i + 1] = hi;
  }
}

// ---------------------------------------------------------------------------
// Fallback: direct NCHW gather (only if workspace too small).
// ---------------------------------------------------------------------------
__global__ __launch_bounds__(256) void roi_align_nchw(
    const float* __restrict__ x, const float* __restrict__ rois,
    float* __restrict__ out, int total) {
  int idx = blockIdx.x * 256 + threadIdx.x;
  if (idx >= total) return;
  int k  = idx / OUT_PER_ROI;
  int rr = idx - k * OUT_PER_ROI;
  int c  = rr / PBINS;
  int p  = rr - c * PBINS;
  int ph = p / 7, pw = p - 7 * ph;
  const float* r = rois + 5 * k;
  int   n  = (int)r[0];
  float sx = r[1] * 0.0625f, sy = r[2] * 0.0625f;
  float ex = r[3] * 0.0625f, ey = r[4] * 0.0625f;
  float rw = fmaxf(ex - sx, 1.0f);
  float rh = fmaxf(ey - sy, 1.0f);
  const float* xb = x + ((size_t)n * CCH + c) * HW;
  float acc = 0.f;
  for (int iy = 0; iy < 2; ++iy) {
    float g  = (float)(2 * ph + iy) + 0.5f;
    float v  = sy + (rh / 7.0f) * (g * 0.5f);
    if (!(v > -1.0f && v < 128.0f)) continue;
    float vc = fminf(fmaxf(v, 0.0f), 127.0f);
    int   y0 = (int)floorf(vc);
    int   y1 = min(y0 + 1, 127);
    float fy = vc - (float)y0;
    for (int ix = 0; ix < 2; ++ix) {
      float gx  = (float)(2 * pw + ix) + 0.5f;
      float vx_ = sx + (rw / 7.0f) * (gx * 0.5f);
      if (!(vx_ > -1.0f && vx_ < 128.0f)) continue;
      float vcx = fminf(fmaxf(vx_, 0.0f), 127.0f);
      int   x0  = (int)floorf(vcx);
      int   x1  = min(x0 + 1, 127);
      float fx  = vcx - (float)x0;
      float v00 = xb[y0 * WW + x0], v01 = xb[y0 * WW + x1];
      float v10 = xb[y1 * WW + x0], v11 = xb[y1 * WW + x1];
      acc += v00 * (1.f - fy) * (1.f - fx) + v01 * (1.f - fy) * fx +
             v10 * fy * (1.f - fx) + v11 * fy * fx;
    }
  }
  out[idx] = acc * 0.25f;
}

extern "C" void kernel_launch(void* const* d_in, const int* in_sizes, int n_in,
                              void* d_out, int out_size, void* d_ws, size_t ws_size,
                              hipStream_t stream) {
  const float* x    = (const float*)d_in[0];
  const float* rois = (const float*)d_in[1];
  float*       out  = (float*)d_out;
  const int K = in_sizes[1] / 5;

  const size_t need = (size_t)NB * CHW * sizeof(float);  // 64 MB
  if (ws_size >= need) {
    float* xt = (float*)d_ws;
    dim3 tb(16, 16, 1);
    dim3 tg(HW / 64, CCH / 64, NB);  // 256 x 4 x 4
    xpose_nchw_nhwc<<<tg, tb, 0, stream>>>(x, xt);
    roi_align_nhwc<<<K, 512, 0, stream>>>(xt, rois, out);
  } else {
    const int total = K * OUT_PER_ROI;
    roi_align_nchw<<<(total + 255) / 256, 256, 0, stream>>>(x, rois, out, total);
  }
}

// Round 6
// 141.291 us; speedup vs baseline: 1.2640x; 1.0481x over previous
//
#include <hip/hip_runtime.h>

// x: (N=4, C=256, H=128, W=128) f32 NCHW; rois: (K,5) f32; out: (K,256,7,7) f32
#define NB    4
#define CCH   256
#define HH    128
#define WW    128
#define HW    (HH * WW)           // 16384
#define CHW   (CCH * HW)          // 4194304 = 1<<22
#define PBINS 49                  // 7*7
#define OUT_PER_ROI (CCH * PBINS) // 12544

typedef __attribute__((ext_vector_type(8))) unsigned short ushort8_t;

__device__ __forceinline__ unsigned short f2bf(float f) {
  unsigned u = __float_as_uint(f);
  unsigned r = u + 0x7fffu + ((u >> 16) & 1u);   // round-to-nearest-even
  return (unsigned short)(r >> 16);
}
__device__ __forceinline__ float bf2f(unsigned short u) {
  return __uint_as_float((unsigned)u << 16);
}
__device__ __forceinline__ float4 ld4bf(const unsigned short* p) {
  ushort4 v = *(const ushort4*)p;                 // 8B load (4 bf16)
  return make_float4(bf2f(v.x), bf2f(v.y), bf2f(v.z), bf2f(v.w));
}

// ---------------------------------------------------------------------------
// Kernel 1: NCHW f32 -> NHWC bf16 transpose, 64ch x 64hw tiles (validated in
// round 4: absmax unchanged at 0.015625). float4 loads, ushort8 16B stores.
// ---------------------------------------------------------------------------
__global__ __launch_bounds__(256) void xpose_nchw_nhwc_bf16(
    const float* __restrict__ src, unsigned short* __restrict__ dst) {
  __shared__ float tile[64][65];
  const int n   = blockIdx.z;
  const int hw0 = blockIdx.x * 64;
  const int c0  = blockIdx.y * 64;
  const float* s = src + (size_t)n * CHW;
  unsigned short* d = dst + (size_t)n * CHW;
  const int tid = threadIdx.x;
  const int tx = tid & 15, ty = tid >> 4;        // 16 x 16

#pragma unroll
  for (int r = 0; r < 4; ++r) {
    const int c = ty + 16 * r;                   // 0..63
    const float4 v = *(const float4*)(s + (size_t)(c0 + c) * HW + hw0 + 4 * tx);
    tile[c][4 * tx + 0] = v.x;
    tile[c][4 * tx + 1] = v.y;
    tile[c][4 * tx + 2] = v.z;
    tile[c][4 * tx + 3] = v.w;
  }
  __syncthreads();

  const int row = tid >> 3;                      // 0..31 (hw within tile)
  const int cg  = tid & 7;                       // channel group of 8
#pragma unroll
  for (int r = 0; r < 2; ++r) {
    const int h = row + 32 * r;                  // 0..63
    ushort8_t o;
#pragma unroll
    for (int j = 0; j < 8; ++j) o[j] = f2bf(tile[cg * 8 + j][h]);
    *(ushort8_t*)(d + (size_t)(hw0 + h) * CCH + c0 + cg * 8) = o;
  }
}

// ---------------------------------------------------------------------------
// Kernel 2: ROI align over bf16 NHWC map — round-5 structure verbatim, with
// ONE change: xt is bf16 (ushort4 8B corner loads instead of float4 16B).
// bf16 s_pool (25.6KB LDS -> 4 blocks/CU) kept from round 5.
// ---------------------------------------------------------------------------
__global__ __launch_bounds__(512) void roi_align_nhwc(
    const unsigned short* __restrict__ xt, const float* __restrict__ rois,
    float* __restrict__ out) {
  __shared__ unsigned short s_pool[OUT_PER_ROI];   // 24.5 KB (bf16)
  __shared__ float s_fy[14], s_fx[14];
  __shared__ int   s_y0[14], s_y1[14], s_x0[14], s_x1[14], s_vy[14], s_vx[14];

  const int k   = blockIdx.x;
  const int tid = threadIdx.x;
  const float* r = rois + 5 * k;
  const int   n  = (int)r[0];
  const float sx = r[1] * 0.0625f, sy = r[2] * 0.0625f;
  const float ex = r[3] * 0.0625f, ey = r[4] * 0.0625f;
  const float rw = fmaxf(ex - sx, 1.0f);
  const float rh = fmaxf(ey - sy, 1.0f);

  if (tid < 14) {                       // y metadata
    float g  = ((float)tid + 0.5f) * 0.5f;
    float v  = sy + (rh / 7.0f) * g;
    int   ok = (v > -1.0f) && (v < 128.0f);
    float vc = fminf(fmaxf(v, 0.0f), 127.0f);
    int   lo = (int)floorf(vc);
    s_y0[tid] = lo;
    s_y1[tid] = min(lo + 1, 127);
    s_fy[tid] = vc - (float)lo;
    s_vy[tid] = ok;
  } else if (tid >= 64 && tid < 78) {   // x metadata
    int   j  = tid - 64;
    float g  = ((float)j + 0.5f) * 0.5f;
    float v  = sx + (rw / 7.0f) * g;
    int   ok = (v > -1.0f) && (v < 128.0f);
    float vc = fminf(fmaxf(v, 0.0f), 127.0f);
    int   lo = (int)floorf(vc);
    s_x0[j] = lo;
    s_x1[j] = min(lo + 1, 127);
    s_fx[j] = vc - (float)lo;
    s_vx[j] = ok;
  }
  __syncthreads();

  const int wv   = tid >> 6;            // 0..7
  const int lane = tid & 63;
  const unsigned short* xbase = xt + ((size_t)n << 22) + (lane << 2);

  for (int p = wv; p < PBINS; p += 8) {
    const int ph = p / 7;
    const int pw = p - 7 * ph;
    float a0 = 0.f, a1 = 0.f, a2 = 0.f, a3 = 0.f;
#pragma unroll
    for (int iy = 0; iy < 2; ++iy) {
      const int   gy = 2 * ph + iy;
      const int   vy = s_vy[gy];
      const float fy = s_fy[gy];
      const int   y0 = s_y0[gy], y1 = s_y1[gy];
#pragma unroll
      for (int ix = 0; ix < 2; ++ix) {
        const int gx = 2 * pw + ix;
        if (vy && s_vx[gx]) {
          const float fx = s_fx[gx];
          const int   x0 = s_x0[gx], x1 = s_x1[gx];
          const float4 v00 = ld4bf(xbase + (y0 << 15) + (x0 << 8));
          const float4 v01 = ld4bf(xbase + (y0 << 15) + (x1 << 8));
          const float4 v10 = ld4bf(xbase + (y1 << 15) + (x0 << 8));
          const float4 v11 = ld4bf(xbase + (y1 << 15) + (x1 << 8));
          const float w00 = (1.f - fy) * (1.f - fx);
          const float w01 = (1.f - fy) * fx;
          const float w10 = fy * (1.f - fx);
          const float w11 = fy * fx;
          a0 += w00 * v00.x + w01 * v01.x + w10 * v10.x + w11 * v11.x;
          a1 += w00 * v00.y + w01 * v01.y + w10 * v10.y + w11 * v11.y;
          a2 += w00 * v00.z + w01 * v01.z + w10 * v10.z + w11 * v11.z;
          a3 += w00 * v00.w + w01 * v01.w + w10 * v10.w + w11 * v11.w;
        }
      }
    }
    const int cb = lane << 2;
    s_pool[(cb + 0) * PBINS + p] = f2bf(a0 * 0.25f);
    s_pool[(cb + 1) * PBINS + p] = f2bf(a1 * 0.25f);
    s_pool[(cb + 2) * PBINS + p] = f2bf(a2 * 0.25f);
    s_pool[(cb + 3) * PBINS + p] = f2bf(a3 * 0.25f);
  }
  __syncthreads();

  // Expand bf16 pool -> f32 output; contiguous 32B per lane per iteration.
  float4*          op = (float4*)(out + (size_t)k * OUT_PER_ROI);
  const ushort8_t* sp = (const ushort8_t*)s_pool;
  for (int i = tid; i < OUT_PER_ROI / 8; i += 512) {   // 1568
    const ushort8_t v = sp[i];
    float4 lo, hi;
    lo.x = bf2f(v[0]); lo.y = bf2f(v[1]); lo.z = bf2f(v[2]); lo.w = bf2f(v[3]);
    hi.x = bf2f(v[4]); hi.y = bf2f(v[5]); hi.z = bf2f(v[6]); hi.w = bf2f(v[7]);
    op[2 * i]     = lo;
    op[2 * i + 1] = hi;
  }
}

// ---------------------------------------------------------------------------
// Fallback: direct NCHW gather (only if workspace too small).
// ---------------------------------------------------------------------------
__global__ __launch_bounds__(256) void roi_align_nchw(
    const float* __restrict__ x, const float* __restrict__ rois,
    float* __restrict__ out, int total) {
  int idx = blockIdx.x * 256 + threadIdx.x;
  if (idx >= total) return;
  int k  = idx / OUT_PER_ROI;
  int rr = idx - k * OUT_PER_ROI;
  int c  = rr / PBINS;
  int p  = rr - c * PBINS;
  int ph = p / 7, pw = p - 7 * ph;
  const float* r = rois + 5 * k;
  int   n  = (int)r[0];
  float sx = r[1] * 0.0625f, sy = r[2] * 0.0625f;
  float ex = r[3] * 0.0625f, ey = r[4] * 0.0625f;
  float rw = fmaxf(ex - sx, 1.0f);
  float rh = fmaxf(ey - sy, 1.0f);
  const float* xb = x + ((size_t)n * CCH + c) * HW;
  float acc = 0.f;
  for (int iy = 0; iy < 2; ++iy) {
    float g  = (float)(2 * ph + iy) + 0.5f;
    float v  = sy + (rh / 7.0f) * (g * 0.5f);
    if (!(v > -1.0f && v < 128.0f)) continue;
    float vc = fminf(fmaxf(v, 0.0f), 127.0f);
    int   y0 = (int)floorf(vc);
    int   y1 = min(y0 + 1, 127);
    float fy = vc - (float)y0;
    for (int ix = 0; ix < 2; ++ix) {
      float gx  = (float)(2 * pw + ix) + 0.5f;
      float vx_ = sx + (rw / 7.0f) * (gx * 0.5f);
      if (!(vx_ > -1.0f && vx_ < 128.0f)) continue;
      float vcx = fminf(fmaxf(vx_, 0.0f), 127.0f);
      int   x0  = (int)floorf(vcx);
      int   x1  = min(x0 + 1, 127);
      float fx  = vcx - (float)x0;
      float v00 = xb[y0 * WW + x0], v01 = xb[y0 * WW + x1];
      float v10 = xb[y1 * WW + x0], v11 = xb[y1 * WW + x1];
      acc += v00 * (1.f - fy) * (1.f - fx) + v01 * (1.f - fy) * fx +
             v10 * fy * (1.f - fx) + v11 * fy * fx;
    }
  }
  out[idx] = acc * 0.25f;
}

extern "C" void kernel_launch(void* const* d_in, const int* in_sizes, int n_in,
                              void* d_out, int out_size, void* d_ws, size_t ws_size,
                              hipStream_t stream) {
  const float* x    = (const float*)d_in[0];
  const float* rois = (const float*)d_in[1];
  float*       out  = (float*)d_out;
  const int K = in_sizes[1] / 5;

  const size_t need = (size_t)NB * CHW * sizeof(unsigned short);  // 32 MB
  if (ws_size >= need) {
    unsigned short* xt = (unsigned short*)d_ws;
    dim3 tb(256, 1, 1);
    dim3 tg(HW / 64, CCH / 64, NB);  // 256 x 4 x 4
    xpose_nchw_nhwc_bf16<<<tg, tb, 0, stream>>>(x, xt);
    roi_align_nhwc<<<K, 512, 0, stream>>>(xt, rois, out);
  } else {
    const int total = K * OUT_PER_ROI;
    roi_align_nchw<<<(total + 255) / 256, 256, 0, stream>>>(x, rois, out, total);
  }
}